// Round 7
// baseline (841.040 us; speedup 1.0000x reference)
//
#include <hip/hip_runtime.h>
#include <hip/hip_bf16.h>
#include <math.h>

// ---------------------------------------------------------------------------
// Mamba2 forward. Pre-split bf16 operands + pure-bf16 3-pass MFMA GEMMs +
// MFMA chunked (SSD) scan.
// Pipeline:
//   K0a split_x        : x -> xh/xl bf16            (into conv region)
//   K0b split_transpose: W_in[:,0:4224] -> wht/wlt [n][k] (conv region)
//   K1  gemm_bf16pre   : zx = x @ W_in[:,0:4224]    (bf16 hi/lo operands)
//   K2  dt_kernel      : dt=softplus(x·w+b); dtA=dt*A      (fp32 exact)
//   K3  conv_kernel    : conv = silu(depthwise conv4 + b)  (overwrites splits)
//   K4a chunk_intra    : per (b,h,c) all-MFMA intra-chunk tile
//   K4b state_scan     : inter-chunk recurrence
//   K4c chunk_out      : Y += exp(la)*C@sin + D*x
//   K0c split_transpose: W_out -> woth/wotl [n][k]  (into Sbuf region, dead)
//   K5  norm_kernel    : g=y*silu(z); RMSNorm -> ynh/ynl bf16 (conv region)
//   K6  gemm_bf16pre   : out = yn @ W_out
// ws unchanged: 246,415,360 bytes. All split buffers alias dead regions.
// ---------------------------------------------------------------------------

#define LSTRIDE 4224
#define CSTRIDE 2176
#define MROWS   8192
#define QCH     128
#define NCH     32

typedef __attribute__((ext_vector_type(8))) short bf16x8;
typedef __attribute__((ext_vector_type(4))) float f32x4;

static __device__ __forceinline__ ushort f2bf_rne(float f) {
  unsigned u = __float_as_uint(f);
  unsigned r = (u + 0x7fffu + ((u >> 16) & 1u)) >> 16;
  return (ushort)r;
}
static __device__ __forceinline__ float bf2f(ushort u) {
  return __uint_as_float(((unsigned)u) << 16);
}
static __device__ __forceinline__ void split4(float4 v, ushort4& h, ushort4& l) {
  h.x = f2bf_rne(v.x); l.x = f2bf_rne(v.x - bf2f(h.x));
  h.y = f2bf_rne(v.y); l.y = f2bf_rne(v.y - bf2f(h.y));
  h.z = f2bf_rne(v.z); l.z = f2bf_rne(v.z - bf2f(h.z));
  h.w = f2bf_rne(v.w); l.w = f2bf_rne(v.w - bf2f(h.w));
}

// XOR swizzles (granule = 8 ushorts = 16B), 2-way-max on b128 access
#define SWI(r,k) ((r)*64  + ((k) ^ (((r)&7)<<3)))   // [128][64] ushort tile
#define CBI(r,k) ((r)*64  + ((k) ^ (((r)&7)<<3)))   // chunk_intra [128][64]
#define TXI(p,j) ((p)*128 + ((j) ^ (((p)&7)<<3)))   // chunk_intra [*][128]

// ----------------- K0a: elementwise fp32 -> bf16 hi/lo ---------------------
__global__ __launch_bounds__(256) void split_x(
    const float* __restrict__ x, ushort* __restrict__ xh,
    ushort* __restrict__ xl, int n4) {
  int i = blockIdx.x * 256 + threadIdx.x;
  const int stride = gridDim.x * 256;
  for (; i < n4; i += stride) {
    float4 v = ((const float4*)x)[i];
    ushort4 h, l;
    split4(v, h, l);
    *(ushort4*)(xh + (size_t)i * 4) = h;
    *(ushort4*)(xl + (size_t)i * 4) = l;
  }
}

// ------- K0b/K0c: split + transpose  src[K][N] fp32 -> dst[N][K] bf16 ------
__global__ __launch_bounds__(256) void split_transpose(
    const float* __restrict__ src, int ldsrc,
    ushort* __restrict__ dh, ushort* __restrict__ dl, int Kd) {
  __shared__ float Ls[64][68];
  const int n0 = blockIdx.x * 64, k0 = blockIdx.y * 64;
  const int t = threadIdx.x;
  {
    const int kr = t >> 2, f = t & 3;
    const float* p = src + (size_t)(k0 + kr) * ldsrc + n0 + f * 16;
    #pragma unroll
    for (int q = 0; q < 4; ++q)
      *(float4*)&Ls[kr][f * 16 + q * 4] = *(const float4*)(p + q * 4);
  }
  __syncthreads();
  const int nr = t & 63, part = t >> 6;   // 16 k per thread
  ushort hv[16], lv[16];
  #pragma unroll
  for (int i = 0; i < 16; ++i) {
    float v = Ls[part * 16 + i][nr];
    hv[i] = f2bf_rne(v);
    lv[i] = f2bf_rne(v - bf2f(hv[i]));
  }
  const size_t off = (size_t)(n0 + nr) * Kd + k0 + part * 16;
  *(bf16x8*)(dh + off)     = ((bf16x8*)hv)[0];
  *(bf16x8*)(dh + off + 8) = ((bf16x8*)hv)[1];
  *(bf16x8*)(dl + off)     = ((bf16x8*)lv)[0];
  *(bf16x8*)(dl + off + 8) = ((bf16x8*)lv)[1];
}

// ------- K1/K6: pure-bf16 3-pass MFMA GEMM, 128x128 tile, BK=64 ------------
// A: [M][K] bf16 hi/lo (row-major). B: [N][K] bf16 hi/lo (pre-transposed).
__global__ __launch_bounds__(256) void gemm_bf16pre(
    const ushort* __restrict__ Ah_g, const ushort* __restrict__ Al_g,
    const ushort* __restrict__ Bh_g, const ushort* __restrict__ Bl_g,
    float* __restrict__ C, int K, int ldc) {
  __shared__ ushort As[2][8192];   // hi, lo  [128][64] swizzled
  __shared__ ushort Bs[2][8192];

  const int tid  = threadIdx.x;
  const int lane = tid & 63;
  const int wid  = tid >> 6;
  const int wm   = wid >> 1, wn = wid & 1;
  const int bm   = blockIdx.y * 128, bn = blockIdx.x * 128;
  const int lr   = lane & 15, l4 = lane >> 4, lq4 = (lane >> 4) * 4;
  const int srow = tid >> 1, skh = (tid & 1) * 32;

  f32x4 acc[4][4];
  #pragma unroll
  for (int m = 0; m < 4; ++m)
    #pragma unroll
    for (int n = 0; n < 4; ++n) acc[m][n] = (f32x4)0.f;

  for (int k0 = 0; k0 < K; k0 += 64) {
    bf16x8 va[4][2], vb[4][2];
    #pragma unroll
    for (int f = 0; f < 4; ++f) {
      const size_t ka = (size_t)(bm + srow) * K + k0 + skh + f * 8;
      va[f][0] = *(const bf16x8*)(Ah_g + ka);
      va[f][1] = *(const bf16x8*)(Al_g + ka);
      const size_t kb2 = (size_t)(bn + srow) * K + k0 + skh + f * 8;
      vb[f][0] = *(const bf16x8*)(Bh_g + kb2);
      vb[f][1] = *(const bf16x8*)(Bl_g + kb2);
    }
    __syncthreads();
    #pragma unroll
    for (int f = 0; f < 4; ++f) {
      const int kk = skh + f * 8;
      *(bf16x8*)&As[0][SWI(srow, kk)] = va[f][0];
      *(bf16x8*)&As[1][SWI(srow, kk)] = va[f][1];
      *(bf16x8*)&Bs[0][SWI(srow, kk)] = vb[f][0];
      *(bf16x8*)&Bs[1][SWI(srow, kk)] = vb[f][1];
    }
    __syncthreads();
    #pragma unroll
    for (int ks = 0; ks < 2; ++ks) {
      const int kb = ks * 32 + l4 * 8;
      bf16x8 fa[4][2], fb[4][2];
      #pragma unroll
      for (int m = 0; m < 4; ++m) {
        const int row = wm * 64 + m * 16 + lr;
        fa[m][0] = *(const bf16x8*)&As[0][SWI(row, kb)];
        fa[m][1] = *(const bf16x8*)&As[1][SWI(row, kb)];
      }
      #pragma unroll
      for (int n = 0; n < 4; ++n) {
        const int col = wn * 64 + n * 16 + lr;
        fb[n][0] = *(const bf16x8*)&Bs[0][SWI(col, kb)];
        fb[n][1] = *(const bf16x8*)&Bs[1][SWI(col, kb)];
      }
      #pragma unroll
      for (int m = 0; m < 4; ++m)
        #pragma unroll
        for (int n = 0; n < 4; ++n) {
          acc[m][n] = __builtin_amdgcn_mfma_f32_16x16x32_bf16(fa[m][0], fb[n][0], acc[m][n], 0, 0, 0);
          acc[m][n] = __builtin_amdgcn_mfma_f32_16x16x32_bf16(fa[m][0], fb[n][1], acc[m][n], 0, 0, 0);
          acc[m][n] = __builtin_amdgcn_mfma_f32_16x16x32_bf16(fa[m][1], fb[n][0], acc[m][n], 0, 0, 0);
        }
    }
  }

  #pragma unroll
  for (int m = 0; m < 4; ++m) {
    const int rbase = bm + wm * 64 + m * 16 + lq4;
    #pragma unroll
    for (int n = 0; n < 4; ++n) {
      const int col = bn + wn * 64 + n * 16 + lr;
      #pragma unroll
      for (int q = 0; q < 4; ++q)
        C[(size_t)(rbase + q) * ldc + col] = acc[m][n][q];
    }
  }
}

// ----------------- K2: dt columns (fp32 dot) + softplus + dtA --------------
__global__ __launch_bounds__(256) void dt_kernel(
    const float* __restrict__ x, const float* __restrict__ W_in,
    const float* __restrict__ dt_bias, const float* __restrict__ A_log,
    float* __restrict__ dt_buf, float* __restrict__ dtA_buf) {
  __shared__ float xs[1024];
  __shared__ float red[8][32];
  const int m = blockIdx.x, tid = threadIdx.x;
  const float* xr = x + (size_t)m * 1024;
  *(float4*)&xs[tid * 4] = *(const float4*)&xr[tid * 4];
  __syncthreads();
  const int h = tid & 31, part = tid >> 5;
  const float* w = W_in + 4224 + h;
  float acc = 0.f;
  const int kb = part * 128;
  #pragma unroll 4
  for (int k = kb; k < kb + 128; ++k) acc = fmaf(xs[k], w[(size_t)k * 4256], acc);
  red[part][h] = acc;
  __syncthreads();
  if (tid < 32) {
    float v = 0.f;
    #pragma unroll
    for (int p = 0; p < 8; ++p) v += red[p][tid];
    v += dt_bias[tid];
    float sp = v > 20.f ? v : log1pf(expf(v));
    float An = -expf(A_log[tid]);
    dt_buf[(size_t)m * 32 + tid] = sp;
    dtA_buf[(size_t)m * 32 + tid] = sp * An;
  }
}

// ----------------- K3: causal depthwise conv4 + bias + silu ----------------
__global__ __launch_bounds__(256) void conv_kernel(
    const float* __restrict__ zx, const float* __restrict__ cw,
    const float* __restrict__ cb, float* __restrict__ conv) {
  const int c = blockIdx.x * 256 + threadIdx.x;
  if (c >= CSTRIDE) return;
  const int m = blockIdx.y;
  const int l = m & 4095;
  float acc = cb[c];
  const float* src = zx + (size_t)m * LSTRIDE + 2048 + c;
  #pragma unroll
  for (int k = 0; k < 4; ++k) {
    int lk = l - 3 + k;
    if (lk >= 0) acc = fmaf(src[(size_t)(k - 3) * LSTRIDE], cw[c * 4 + k], acc);
  }
  float s = acc / (1.f + expf(-acc));
  conv[(size_t)m * CSTRIDE + c] = s;
}

// --------- K4a: intra-chunk, all-MFMA (split-bf16 3-pass) ------------------
__global__ __launch_bounds__(256) void chunk_intra(
    const float* __restrict__ conv, const float* __restrict__ dtb,
    const float* __restrict__ dtAb, float* __restrict__ zx,
    float* __restrict__ Sbuf, float* __restrict__ labuf) {
  __shared__ ushort pool1[32768];
  __shared__ ushort pool2[32768];
  __shared__ float las[128], dts[128], fqs[128];

  ushort* Chi = pool1;
  ushort* Clo = pool1 + 8192;
  ushort* Bhi = pool1 + 16384;
  ushort* Blo = pool1 + 24576;
  ushort* Whi = pool1;
  ushort* Wlo = pool1 + 16384;
  ushort* Xth = pool2;
  ushort* Xtl = pool2 + 8192;
  ushort* Bfh = pool2 + 16384;
  ushort* Bfl = pool2 + 24576;

  const int tid  = threadIdx.x;
  const int lane = tid & 63;
  const int w    = tid >> 6;
  const int l15  = lane & 15;
  const int l4   = lane >> 4;
  const int c    = blockIdx.x & 31;
  const int hh   = (blockIdx.x >> 5) & 31;
  const int b    = blockIdx.x >> 10;
  const size_t m0 = (size_t)b * 4096 + c * QCH;
  const int slot  = (b * 32 + hh) * NCH + c;

  if (tid < 128) {
    dts[tid] = dtb[(m0 + tid) * 32 + hh];
    las[tid] = dtAb[(m0 + tid) * 32 + hh];
  }
  __syncthreads();
  for (int ofs = 1; ofs < 128; ofs <<= 1) {
    float v = 0.f;
    if (tid < 128 && tid >= ofs) v = las[tid - ofs];
    __syncthreads();
    if (tid < 128) las[tid] += v;
    __syncthreads();
  }
  if (tid < 128) {
    fqs[tid] = __expf(las[127] - las[tid]) * dts[tid];
    labuf[(size_t)slot * 128 + tid] = las[tid];
  }
  __syncthreads();

  {
    const int r = tid & 127, hf = tid >> 7;
    const float* rowp = conv + (m0 + r) * CSTRIDE;
    const float fqr = fqs[r];
    #pragma unroll
    for (int f = 0; f < 8; ++f) {
      const int c0 = hf * 32 + f * 4;
      float4 vc = *(const float4*)(rowp + 2112 + c0);
      ushort4 h, l;
      split4(vc, h, l);
      *(ushort4*)(Chi + CBI(r, c0)) = h;
      *(ushort4*)(Clo + CBI(r, c0)) = l;
      float4 vb = *(const float4*)(rowp + 2048 + c0);
      split4(vb, h, l);
      *(ushort4*)(Bhi + CBI(r, c0)) = h;
      *(ushort4*)(Blo + CBI(r, c0)) = l;
      float fb[4] = {vb.x * fqr, vb.y * fqr, vb.z * fqr, vb.w * fqr};
      #pragma unroll
      for (int e = 0; e < 4; ++e) {
        ushort hh2 = f2bf_rne(fb[e]);
        Bfh[TXI(c0 + e, r)] = hh2;
        Bfl[TXI(c0 + e, r)] = f2bf_rne(fb[e] - bf2f(hh2));
      }
      float4 vx = *(const float4*)(rowp + hh * 64 + c0);
      float fx[4] = {vx.x, vx.y, vx.z, vx.w};
      #pragma unroll
      for (int e = 0; e < 4; ++e) {
        ushort hh2 = f2bf_rne(fx[e]);
        Xth[TXI(c0 + e, r)] = hh2;
        Xtl[TXI(c0 + e, r)] = f2bf_rne(fx[e] - bf2f(hh2));
      }
    }
  }
  __syncthreads();

  f32x4 g[2][8];
  #pragma unroll
  for (int ti = 0; ti < 2; ++ti)
    #pragma unroll
    for (int tj = 0; tj < 8; ++tj) g[ti][tj] = (f32x4)0.f;

  #pragma unroll
  for (int ks = 0; ks < 2; ++ks) {
    const int kb = ks * 32 + l4 * 8;
    bf16x8 ca[2][2], bb[8][2];
    #pragma unroll
    for (int ti = 0; ti < 2; ++ti) {
      const int row = 32 * w + ti * 16 + l15;
      ca[ti][0] = *(const bf16x8*)(Chi + CBI(row, kb));
      ca[ti][1] = *(const bf16x8*)(Clo + CBI(row, kb));
    }
    #pragma unroll
    for (int tj = 0; tj < 8; ++tj) {
      const int jr = tj * 16 + l15;
      bb[tj][0] = *(const bf16x8*)(Bhi + CBI(jr, kb));
      bb[tj][1] = *(const bf16x8*)(Blo + CBI(jr, kb));
    }
    #pragma unroll
    for (int ti = 0; ti < 2; ++ti)
      #pragma unroll
      for (int tj = 0; tj < 8; ++tj) {
        g[ti][tj] = __builtin_amdgcn_mfma_f32_16x16x32_bf16(ca[ti][0], bb[tj][0], g[ti][tj], 0, 0, 0);
        g[ti][tj] = __builtin_amdgcn_mfma_f32_16x16x32_bf16(ca[ti][0], bb[tj][1], g[ti][tj], 0, 0, 0);
        g[ti][tj] = __builtin_amdgcn_mfma_f32_16x16x32_bf16(ca[ti][1], bb[tj][0], g[ti][tj], 0, 0, 0);
      }
  }
  __syncthreads();

  #pragma unroll
  for (int ti = 0; ti < 2; ++ti) {
    const int ib = 32 * w + ti * 16 + l4 * 4;
    #pragma unroll
    for (int tj = 0; tj < 8; ++tj) {
      const int j = tj * 16 + l15;
      const float laj = las[j], dj = dts[j];
      #pragma unroll
      for (int q = 0; q < 4; ++q) {
        const int i = ib + q;
        float wv = (j <= i) ? g[ti][tj][q] * __expf(las[i] - laj) * dj : 0.f;
        ushort h = f2bf_rne(wv);
        Whi[TXI(i, j)] = h;
        Wlo[TXI(i, j)] = f2bf_rne(wv - bf2f(h));
      }
    }
  }

  f32x4 y[2][4];
  #pragma unroll
  for (int ti = 0; ti < 2; ++ti)
    #pragma unroll
    for (int tp = 0; tp < 4; ++tp) y[ti][tp] = (f32x4)0.f;

  #pragma unroll
  for (int ks = 0; ks < 4; ++ks) {
    const int kb = ks * 32 + l4 * 8;
    bf16x8 wa[2][2], xb[4][2];
    #pragma unroll
    for (int ti = 0; ti < 2; ++ti) {
      const int row = 32 * w + ti * 16 + l15;
      wa[ti][0] = *(const bf16x8*)(Whi + TXI(row, kb));
      wa[ti][1] = *(const bf16x8*)(Wlo + TXI(row, kb));
    }
    #pragma unroll
    for (int tp = 0; tp < 4; ++tp) {
      const int p = tp * 16 + l15;
      xb[tp][0] = *(const bf16x8*)(Xth + TXI(p, kb));
      xb[tp][1] = *(const bf16x8*)(Xtl + TXI(p, kb));
    }
    #pragma unroll
    for (int ti = 0; ti < 2; ++ti)
      #pragma unroll
      for (int tp = 0; tp < 4; ++tp) {
        y[ti][tp] = __builtin_amdgcn_mfma_f32_16x16x32_bf16(wa[ti][0], xb[tp][0], y[ti][tp], 0, 0, 0);
        y[ti][tp] = __builtin_amdgcn_mfma_f32_16x16x32_bf16(wa[ti][0], xb[tp][1], y[ti][tp], 0, 0, 0);
        y[ti][tp] = __builtin_amdgcn_mfma_f32_16x16x32_bf16(wa[ti][1], xb[tp][0], y[ti][tp], 0, 0, 0);
      }
  }
  #pragma unroll
  for (int ti = 0; ti < 2; ++ti) {
    #pragma unroll
    for (int tp = 0; tp < 4; ++tp) {
      const int p = tp * 16 + l15;
      #pragma unroll
      for (int q = 0; q < 4; ++q) {
        const int i = 32 * w + ti * 16 + l4 * 4 + q;
        zx[(m0 + i) * LSTRIDE + 2048 + hh * 64 + p] = y[ti][tp][q];
      }
    }
  }

  f32x4 s[4];
  #pragma unroll
  for (int tn = 0; tn < 4; ++tn) s[tn] = (f32x4)0.f;
  #pragma unroll
  for (int ks = 0; ks < 4; ++ks) {
    const int kb = ks * 32 + l4 * 8;
    bf16x8 xa[2], bf[4][2];
    {
      const int p = 16 * w + l15;
      xa[0] = *(const bf16x8*)(Xth + TXI(p, kb));
      xa[1] = *(const bf16x8*)(Xtl + TXI(p, kb));
    }
    #pragma unroll
    for (int tn = 0; tn < 4; ++tn) {
      const int n = tn * 16 + l15;
      bf[tn][0] = *(const bf16x8*)(Bfh + TXI(n, kb));
      bf[tn][1] = *(const bf16x8*)(Bfl + TXI(n, kb));
    }
    #pragma unroll
    for (int tn = 0; tn < 4; ++tn) {
      s[tn] = __builtin_amdgcn_mfma_f32_16x16x32_bf16(xa[0], bf[tn][0], s[tn], 0, 0, 0);
      s[tn] = __builtin_amdgcn_mfma_f32_16x16x32_bf16(xa[0], bf[tn][1], s[tn], 0, 0, 0);
      s[tn] = __builtin_amdgcn_mfma_f32_16x16x32_bf16(xa[1], bf[tn][0], s[tn], 0, 0, 0);
    }
  }
  #pragma unroll
  for (int tn = 0; tn < 4; ++tn) {
    const int n = tn * 16 + l15;
    #pragma unroll
    for (int q = 0; q < 4; ++q) {
      const int p = 16 * w + l4 * 4 + q;
      Sbuf[(size_t)slot * 4096 + n * 64 + p] = s[tn][q];
    }
  }
}

// --------- K4b: chunk-state recurrence -------------------------------------
__global__ __launch_bounds__(256) void state_scan(
    float* __restrict__ Sbuf, const float* __restrict__ labuf) {
  const int bh = blockIdx.x >> 4;
  const int e  = (blockIdx.x & 15) * 256 + threadIdx.x;
  __shared__ float cq[NCH];
  if (threadIdx.x < NCH)
    cq[threadIdx.x] = __expf(labuf[((size_t)bh * NCH + threadIdx.x) * 128 + 127]);
  __syncthreads();
  float s = 0.f;
  float* base = Sbuf + (size_t)bh * NCH * 4096 + e;
  #pragma unroll 4
  for (int c = 0; c < NCH; ++c) {
    const float sv = base[c * 4096];
    base[c * 4096] = s;
    s = fmaf(cq[c], s, sv);
  }
}

// --------- K4c: Y += exp(la_i) * C @ sin + D*x ------------------------------
__global__ __launch_bounds__(256) void chunk_out(
    const float* __restrict__ conv, const float* __restrict__ Sbuf,
    const float* __restrict__ labuf, const float* __restrict__ Dv,
    float* __restrict__ zx) {
  __shared__ float Ct[64][132];
  __shared__ float Sin[64][65];
  __shared__ float las[128];

  const int tid  = threadIdx.x;
  const int lane = tid & 63;
  const int w    = tid >> 6;
  const int c    = blockIdx.x & 31;
  const int hh   = (blockIdx.x >> 5) & 31;
  const int b    = blockIdx.x >> 10;
  const size_t m0 = (size_t)b * 4096 + c * QCH;
  const int slot  = (b * 32 + hh) * NCH + c;

  {
    const int r = tid & 127, piece = tid >> 7;
    const float* rowp = conv + (m0 + r) * CSTRIDE;
    #pragma unroll
    for (int f = 0; f < 8; ++f) {
      const int n0 = piece * 32 + f * 4;
      float4 v = *(const float4*)(rowp + 2112 + n0);
      Ct[n0][r] = v.x; Ct[n0+1][r] = v.y; Ct[n0+2][r] = v.z; Ct[n0+3][r] = v.w;
    }
    #pragma unroll
    for (int f = 0; f < 4; ++f) {
      const int idx = tid * 16 + f * 4;
      float4 v = *(const float4*)(Sbuf + (size_t)slot * 4096 + idx);
      const int n = idx >> 6, p = idx & 63;
      Sin[n][p] = v.x; Sin[n][p+1] = v.y; Sin[n][p+2] = v.z; Sin[n][p+3] = v.w;
    }
    if (tid < 128) las[tid] = labuf[(size_t)slot * 128 + tid];
  }
  __syncthreads();

  const int r0 = w * 32;
  float acc[32];
  #pragma unroll
  for (int r = 0; r < 32; ++r) acc[r] = 0.f;
  #pragma unroll 2
  for (int n = 0; n < 64; ++n) {
    const float sv = Sin[n][lane];
    #pragma unroll
    for (int r4 = 0; r4 < 8; ++r4) {
      float4 c4 = *(const float4*)&Ct[n][r0 + r4 * 4];
      acc[r4*4+0] = fmaf(c4.x, sv, acc[r4*4+0]);
      acc[r4*4+1] = fmaf(c4.y, sv, acc[r4*4+1]);
      acc[r4*4+2] = fmaf(c4.z, sv, acc[r4*4+2]);
      acc[r4*4+3] = fmaf(c4.w, sv, acc[r4*4+3]);
    }
  }
  const float Dh = Dv[hh];
  #pragma unroll
  for (int r = 0; r < 32; ++r) {
    const int i = r0 + r;
    const size_t off = (m0 + i) * LSTRIDE + 2048 + hh * 64 + lane;
    const float xv = conv[(m0 + i) * CSTRIDE + hh * 64 + lane];
    zx[off] = zx[off] + __expf(las[i]) * acc[r] + Dh * xv;
  }
}

// --------- K4f: fallback serial scan ---------------------------------------
__global__ __launch_bounds__(256) void scan_kernel_fb(
    const float* __restrict__ conv, const float* __restrict__ dt_buf,
    const float* __restrict__ dtA_buf, const float* __restrict__ Dv,
    float* __restrict__ yout) {
  const int wid  = blockIdx.x * 4 + (threadIdx.x >> 6);
  const int lane = threadIdx.x & 63;
  const int b = wid >> 11;
  const int h = (wid >> 6) & 31;
  const int p = wid & 63;
  const size_t m0 = (size_t)b * 4096;
  const float* cx  = conv + m0 * CSTRIDE + h * 64 + p;
  const float* cB  = conv + m0 * CSTRIDE + 2048 + lane;
  const float* cC  = cB + 64;
  const float* cdA = dtA_buf + m0 * 32 + h;
  const float* cdt = dt_buf + m0 * 32 + h;
  float* yo = yout + m0 * LSTRIDE + 2048 + h * 64 + p;
  const float Dh = Dv[h];
  float s = 0.f;
  #pragma unroll 2
  for (int t = 0; t < 4096; ++t) {
    float xv  = cx[(size_t)t * CSTRIDE];
    float Bv  = cB[(size_t)t * CSTRIDE];
    float Cv  = cC[(size_t)t * CSTRIDE];
    float dAv = __expf(cdA[t * 32]);
    float dtv = cdt[t * 32];
    s = fmaf(s, dAv, dtv * xv * Bv);
    float prod = s * Cv;
    #pragma unroll
    for (int msk = 1; msk < 64; msk <<= 1) prod += __shfl_xor(prod, msk, 64);
    if (lane == 0) yo[(size_t)t * LSTRIDE] = fmaf(Dh, xv, prod);
  }
}

// ------- K5: gate + RMSNorm -> bf16 hi/lo (for the K6 bf16 GEMM) -----------
__global__ __launch_bounds__(256) void norm_kernel(
    const float* __restrict__ zx, const float* __restrict__ nw,
    ushort* __restrict__ ynh, ushort* __restrict__ ynl) {
  const int row = blockIdx.x, tid = threadIdx.x;
  const float* z = zx + (size_t)row * LSTRIDE;
  const float* y = z + 2048;
  float g[8];
  float ss = 0.f;
  #pragma unroll
  for (int j = 0; j < 2; ++j) {
    const int col = j * 1024 + tid * 4;
    float4 yv = *(const float4*)&y[col];
    float4 zv = *(const float4*)&z[col];
    float gs[4];
    gs[0] = yv.x * (zv.x / (1.f + expf(-zv.x)));
    gs[1] = yv.y * (zv.y / (1.f + expf(-zv.y)));
    gs[2] = yv.z * (zv.z / (1.f + expf(-zv.z)));
    gs[3] = yv.w * (zv.w / (1.f + expf(-zv.w)));
    #pragma unroll
    for (int q = 0; q < 4; ++q) { g[j * 4 + q] = gs[q]; ss += gs[q] * gs[q]; }
  }
  #pragma unroll
  for (int msk = 1; msk < 64; msk <<= 1) ss += __shfl_xor(ss, msk, 64);
  __shared__ float sred[4];
  if ((tid & 63) == 0) sred[tid >> 6] = ss;
  __syncthreads();
  ss = sred[0] + sred[1] + sred[2] + sred[3];
  const float scale = rsqrtf(ss * (1.f / 2048.f) + 1e-5f);
  #pragma unroll
  for (int j = 0; j < 2; ++j) {
    const int col = j * 1024 + tid * 4;
    float4 ov;
    ov.x = g[j * 4 + 0] * scale * nw[col + 0];
    ov.y = g[j * 4 + 1] * scale * nw[col + 1];
    ov.z = g[j * 4 + 2] * scale * nw[col + 2];
    ov.w = g[j * 4 + 3] * scale * nw[col + 3];
    ushort4 h, l;
    split4(ov, h, l);
    *(ushort4*)(ynh + (size_t)row * 2048 + col) = h;
    *(ushort4*)(ynl + (size_t)row * 2048 + col) = l;
  }
}

// ---------------------------------------------------------------------------
extern "C" void kernel_launch(void* const* d_in, const int* in_sizes, int n_in,
                              void* d_out, int out_size, void* d_ws, size_t ws_size,
                              hipStream_t stream) {
  const float* x       = (const float*)d_in[0];
  const float* W_in    = (const float*)d_in[1];
  const float* conv_w  = (const float*)d_in[2];
  const float* conv_b  = (const float*)d_in[3];
  const float* dt_bias = (const float*)d_in[4];
  const float* A_log   = (const float*)d_in[5];
  const float* Dv      = (const float*)d_in[6];
  const float* nw      = (const float*)d_in[7];
  const float* W_out   = (const float*)d_in[8];
  float* out = (float*)d_out;

  float* zx    = (float*)d_ws;
  float* conv  = zx + (size_t)MROWS * LSTRIDE;
  float* dtb   = conv + (size_t)MROWS * CSTRIDE;
  float* dtAb  = dtb + (size_t)MROWS * 32;
  float* Sbuf  = dtAb + (size_t)MROWS * 32;
  float* labuf = Sbuf + (size_t)64 * NCH * 4096;

  // bf16 split buffers aliasing dead phases of conv / Sbuf regions
  ushort* xh   = (ushort*)conv;               // dead after K1 (K3 overwrites)
  ushort* xl   = xh + 8388608;
  ushort* wht  = xh + 16777216;
  ushort* wlt  = xh + 21102592;
  ushort* ynh  = (ushort*)conv;               // written after K4c consumed conv
  ushort* ynl  = ynh + 16777216;
  ushort* woth = (ushort*)Sbuf;               // written after chunk_out
  ushort* wotl = woth + 2097152;

  const size_t NEED_CHUNKED = 246415360;
  const bool chunked = (ws_size >= NEED_CHUNKED);

  // K0a/K0b: one-time operand split (+transpose for B)
  split_x<<<2048, 256, 0, stream>>>(x, xh, xl, 2097152);
  split_transpose<<<dim3(66, 16), 256, 0, stream>>>(W_in, 4256, wht, wlt, 1024);
  // K1: zx = x @ W_in[:,0:4224]
  gemm_bf16pre<<<dim3(33, 64), 256, 0, stream>>>(xh, xl, wht, wlt, zx, 1024, LSTRIDE);
  // K2: dt (fp32 exact)
  dt_kernel<<<MROWS, 256, 0, stream>>>(x, W_in, dt_bias, A_log, dtb, dtAb);
  // K3: conv (overwrites xh/xl/wht/wlt region)
  conv_kernel<<<dim3(9, MROWS), 256, 0, stream>>>(zx, conv_w, conv_b, conv);

  if (chunked) {
    chunk_intra<<<2048, 256, 0, stream>>>(conv, dtb, dtAb, zx, Sbuf, labuf);
    state_scan<<<1024, 256, 0, stream>>>(Sbuf, labuf);
    chunk_out<<<2048, 256, 0, stream>>>(conv, Sbuf, labuf, Dv, zx);
  } else {
    scan_kernel_fb<<<1024, 256, 0, stream>>>(conv, dtb, dtAb, Dv, zx);
  }

  // K0c: split+transpose W_out into Sbuf region (dead after chunk_out)
  split_transpose<<<dim3(16, 32), 256, 0, stream>>>(W_out, 1024, woth, wotl, 2048);
  // K5: norm -> bf16 hi/lo into conv region (conv dead after K4c)
  norm_kernel<<<MROWS, 256, 0, stream>>>(zx, nw, ynh, ynl);
  // K6: out = yn @ W_out
  gemm_bf16pre<<<dim3(8, 64), 256, 0, stream>>>(ynh, ynl, woth, wotl, out, 2048, 1024);
}

// Round 11
// 818.717 us; speedup vs baseline: 1.0273x; 1.0273x over previous
//
#include <hip/hip_runtime.h>
#include <hip/hip_bf16.h>
#include <math.h>

// ---------------------------------------------------------------------------
// Mamba2 forward. Pre-split bf16 operands + global_load_lds-staged 3-pass
// MFMA GEMMs (BK=32, XCD swizzle) + MFMA chunked (SSD) scan.
// Pipeline:
//   K0a split_x        : x -> xh/xl bf16            (into conv region)
//   K0b split_transpose: W_in[:,0:4224] -> wht/wlt [n][k] (conv region)
//   K1  gemm_bf16pre<128>: zx = x @ W_in[:,0:4224]
//   K2  dt_kernel      : dt=softplus(x·w+b); dtA=dt*A      (fp32 exact)
//   K3  conv_kernel    : conv = silu(depthwise conv4 + b)  (overwrites splits)
//   K4a chunk_intra    : per (b,h,c) all-MFMA intra-chunk tile
//   K4b state_scan     : inter-chunk recurrence
//   K4c chunk_out      : Y += exp(la)*C@sin + D*x
//   K0c split_transpose: W_out -> woth/wotl [n][k]  (into Sbuf region, dead)
//   K5  norm_kernel    : g=y*silu(z); RMSNorm -> ynh/ynl bf16 (conv region)
//   K6  gemm_bf16pre<64>: out = yn @ W_out
// GEMM: BM=128, BK=32, BN template. LDS 4 planes [rows][32] ushort, granule
// swizzle g^=(row&3). Staged via global_load_lds(16B) with pre-swizzled
// per-lane SOURCE (linear LDS dest, rule #21). ws: 246,415,360 B unchanged.
// ---------------------------------------------------------------------------

#define LSTRIDE 4224
#define CSTRIDE 2176
#define MROWS   8192
#define QCH     128
#define NCH     32

typedef __attribute__((ext_vector_type(8))) short bf16x8;
typedef __attribute__((ext_vector_type(4))) float f32x4;

static __device__ __forceinline__ ushort f2bf_rne(float f) {
  unsigned u = __float_as_uint(f);
  unsigned r = (u + 0x7fffu + ((u >> 16) & 1u)) >> 16;
  return (ushort)r;
}
static __device__ __forceinline__ float bf2f(ushort u) {
  return __uint_as_float(((unsigned)u) << 16);
}
static __device__ __forceinline__ void split4(float4 v, ushort4& h, ushort4& l) {
  h.x = f2bf_rne(v.x); l.x = f2bf_rne(v.x - bf2f(h.x));
  h.y = f2bf_rne(v.y); l.y = f2bf_rne(v.y - bf2f(h.y));
  h.z = f2bf_rne(v.z); l.z = f2bf_rne(v.z - bf2f(h.z));
  h.w = f2bf_rne(v.w); l.w = f2bf_rne(v.w - bf2f(h.w));
}
static __device__ __forceinline__ void gload16(const ushort* g, ushort* l) {
  __builtin_amdgcn_global_load_lds(
      (const __attribute__((address_space(1))) int*)g,
      (__attribute__((address_space(3))) int*)l, 16, 0, 0);
}

// BK=32 tile: ushort index, granule(8 ushort)-XOR swizzle by row&3
#define SW32(r,k) ((r)*32 + ((k) ^ (((r)&3)<<3)))
// chunk_intra swizzles (BK=64-row layout, unchanged)
#define CBI(r,k) ((r)*64  + ((k) ^ (((r)&7)<<3)))
#define TXI(p,j) ((p)*128 + ((j) ^ (((p)&7)<<3)))

// ----------------- K0a: elementwise fp32 -> bf16 hi/lo ---------------------
__global__ __launch_bounds__(256) void split_x(
    const float* __restrict__ x, ushort* __restrict__ xh,
    ushort* __restrict__ xl, int n4) {
  int i = blockIdx.x * 256 + threadIdx.x;
  const int stride = gridDim.x * 256;
  for (; i < n4; i += stride) {
    float4 v = ((const float4*)x)[i];
    ushort4 h, l;
    split4(v, h, l);
    *(ushort4*)(xh + (size_t)i * 4) = h;
    *(ushort4*)(xl + (size_t)i * 4) = l;
  }
}

// ------- K0b/K0c: split + transpose  src[K][N] fp32 -> dst[N][K] bf16 ------
__global__ __launch_bounds__(256) void split_transpose(
    const float* __restrict__ src, int ldsrc,
    ushort* __restrict__ dh, ushort* __restrict__ dl, int Kd) {
  __shared__ float Ls[64][68];
  const int n0 = blockIdx.x * 64, k0 = blockIdx.y * 64;
  const int t = threadIdx.x;
  {
    const int kr = t >> 2, f = t & 3;
    const float* p = src + (size_t)(k0 + kr) * ldsrc + n0 + f * 16;
    #pragma unroll
    for (int q = 0; q < 4; ++q)
      *(float4*)&Ls[kr][f * 16 + q * 4] = *(const float4*)(p + q * 4);
  }
  __syncthreads();
  const int nr = t & 63, part = t >> 6;   // 16 k per thread
  ushort hv[16], lv[16];
  #pragma unroll
  for (int i = 0; i < 16; ++i) {
    float v = Ls[part * 16 + i][nr];
    hv[i] = f2bf_rne(v);
    lv[i] = f2bf_rne(v - bf2f(hv[i]));
  }
  const size_t off = (size_t)(n0 + nr) * Kd + k0 + part * 16;
  *(bf16x8*)(dh + off)     = ((bf16x8*)hv)[0];
  *(bf16x8*)(dh + off + 8) = ((bf16x8*)hv)[1];
  *(bf16x8*)(dl + off)     = ((bf16x8*)lv)[0];
  *(bf16x8*)(dl + off + 8) = ((bf16x8*)lv)[1];
}

// ------- K1/K6: bf16 3-pass MFMA GEMM, BM=128, BK=32, BN template ----------
// A: [M][K] bf16 hi/lo row-major. B: [N][K] bf16 hi/lo (pre-transposed).
// global_load_lds staging: linear LDS dest, pre-swizzled per-lane source.
template <int BN>
__global__ __launch_bounds__(256) void gemm_bf16pre(
    const ushort* __restrict__ Ah_g, const ushort* __restrict__ Al_g,
    const ushort* __restrict__ Bh_g, const ushort* __restrict__ Bl_g,
    float* __restrict__ C, int K, int ldc, int nbn) {
  __shared__ ushort As[2][128 * 32];   // hi, lo
  __shared__ ushort Bs[2][BN * 32];

  const int tid  = threadIdx.x;
  const int lane = tid & 63;
  const int w    = tid >> 6;

  // bijective XCD swizzle (grid % 8 == 0 by construction)
  const int cpx  = gridDim.x >> 3;
  const int flat = (blockIdx.x & 7) * cpx + (blockIdx.x >> 3);
  const int bn   = (flat % nbn) * BN;
  const int bm   = (flat / nbn) * 128;

  constexpr int NR = BN / 32;          // per-wave N fragments (2x2 wave grid)
  constexpr int JB = BN / 64;          // B staging issues per wave per plane
  const int wm = w >> 1, wn = w & 1;
  const int lr = lane & 15, l4 = lane >> 4, lq4 = (lane >> 4) * 4;

  // staging lane constants: LDS slot (row, g=lane&3) <- global granule g^(row&3)
  const int gsrc = ((lane & 3) ^ ((lane >> 2) & 3)) * 8;   // ushort offset
  const int arow0 = (w * 2) * 16 + (lane >> 2);            // A issue j adds 16
  const int brow0 = (w * JB) * 16 + (lane >> 2);
  const size_t aoff0 = (size_t)(bm + arow0) * K + gsrc;
  const size_t boff0 = (size_t)(bn + brow0) * K + gsrc;
  const int ldst0 = (w * 2) * 512 + lane * 8;              // ushort linear
  const int bdst0 = (w * JB) * 512 + lane * 8;

  f32x4 acc[4][NR];
  #pragma unroll
  for (int m = 0; m < 4; ++m)
    #pragma unroll
    for (int n = 0; n < NR; ++n) acc[m][n] = (f32x4)0.f;

  for (int k0 = 0; k0 < K; k0 += 32) {
    __syncthreads();   // everyone done reading previous iter's LDS
    #pragma unroll
    for (int j = 0; j < 2; ++j) {
      gload16(Ah_g + aoff0 + (size_t)j * 16 * K + k0, &As[0][ldst0 + j * 512]);
      gload16(Al_g + aoff0 + (size_t)j * 16 * K + k0, &As[1][ldst0 + j * 512]);
    }
    #pragma unroll
    for (int j = 0; j < JB; ++j) {
      gload16(Bh_g + boff0 + (size_t)j * 16 * K + k0, &Bs[0][bdst0 + j * 512]);
      gload16(Bl_g + boff0 + (size_t)j * 16 * K + k0, &Bs[1][bdst0 + j * 512]);
    }
    __syncthreads();   // drains vmcnt -> LDS valid

    const int kb = l4 * 8;
    bf16x8 fa[4][2], fb[NR][2];
    #pragma unroll
    for (int m = 0; m < 4; ++m) {
      const int row = wm * 64 + m * 16 + lr;
      fa[m][0] = *(const bf16x8*)&As[0][SW32(row, kb)];
      fa[m][1] = *(const bf16x8*)&As[1][SW32(row, kb)];
    }
    #pragma unroll
    for (int n = 0; n < NR; ++n) {
      const int col = wn * (BN / 2) + n * 16 + lr;
      fb[n][0] = *(const bf16x8*)&Bs[0][SW32(col, kb)];
      fb[n][1] = *(const bf16x8*)&Bs[1][SW32(col, kb)];
    }
    #pragma unroll
    for (int m = 0; m < 4; ++m)
      #pragma unroll
      for (int n = 0; n < NR; ++n) {
        acc[m][n] = __builtin_amdgcn_mfma_f32_16x16x32_bf16(fa[m][0], fb[n][0], acc[m][n], 0, 0, 0);
        acc[m][n] = __builtin_amdgcn_mfma_f32_16x16x32_bf16(fa[m][0], fb[n][1], acc[m][n], 0, 0, 0);
        acc[m][n] = __builtin_amdgcn_mfma_f32_16x16x32_bf16(fa[m][1], fb[n][0], acc[m][n], 0, 0, 0);
      }
  }

  #pragma unroll
  for (int m = 0; m < 4; ++m) {
    const int rbase = bm + wm * 64 + m * 16 + lq4;
    #pragma unroll
    for (int n = 0; n < NR; ++n) {
      const int col = bn + wn * (BN / 2) + n * 16 + lr;
      #pragma unroll
      for (int q = 0; q < 4; ++q)
        C[(size_t)(rbase + q) * ldc + col] = acc[m][n][q];
    }
  }
}

// ----------------- K2: dt columns (fp32 dot) + softplus + dtA --------------
__global__ __launch_bounds__(256) void dt_kernel(
    const float* __restrict__ x, const float* __restrict__ W_in,
    const float* __restrict__ dt_bias, const float* __restrict__ A_log,
    float* __restrict__ dt_buf, float* __restrict__ dtA_buf) {
  __shared__ float xs[1024];
  __shared__ float red[8][32];
  const int m = blockIdx.x, tid = threadIdx.x;
  const float* xr = x + (size_t)m * 1024;
  *(float4*)&xs[tid * 4] = *(const float4*)&xr[tid * 4];
  __syncthreads();
  const int h = tid & 31, part = tid >> 5;
  const float* w = W_in + 4224 + h;
  float acc = 0.f;
  const int kb = part * 128;
  #pragma unroll 4
  for (int k = kb; k < kb + 128; ++k) acc = fmaf(xs[k], w[(size_t)k * 4256], acc);
  red[part][h] = acc;
  __syncthreads();
  if (tid < 32) {
    float v = 0.f;
    #pragma unroll
    for (int p = 0; p < 8; ++p) v += red[p][tid];
    v += dt_bias[tid];
    float sp = v > 20.f ? v : log1pf(expf(v));
    float An = -expf(A_log[tid]);
    dt_buf[(size_t)m * 32 + tid] = sp;
    dtA_buf[(size_t)m * 32 + tid] = sp * An;
  }
}

// ----------------- K3: causal depthwise conv4 + bias + silu ----------------
__global__ __launch_bounds__(256) void conv_kernel(
    const float* __restrict__ zx, const float* __restrict__ cw,
    const float* __restrict__ cb, float* __restrict__ conv) {
  const int c = blockIdx.x * 256 + threadIdx.x;
  if (c >= CSTRIDE) return;
  const int m = blockIdx.y;
  const int l = m & 4095;
  float acc = cb[c];
  const float* src = zx + (size_t)m * LSTRIDE + 2048 + c;
  #pragma unroll
  for (int k = 0; k < 4; ++k) {
    int lk = l - 3 + k;
    if (lk >= 0) acc = fmaf(src[(size_t)(k - 3) * LSTRIDE], cw[c * 4 + k], acc);
  }
  float s = acc / (1.f + expf(-acc));
  conv[(size_t)m * CSTRIDE + c] = s;
}

// --------- K4a: intra-chunk, all-MFMA (split-bf16 3-pass) ------------------
__global__ __launch_bounds__(256) void chunk_intra(
    const float* __restrict__ conv, const float* __restrict__ dtb,
    const float* __restrict__ dtAb, float* __restrict__ zx,
    float* __restrict__ Sbuf, float* __restrict__ labuf) {
  __shared__ ushort pool1[32768];
  __shared__ ushort pool2[32768];
  __shared__ float las[128], dts[128], fqs[128];

  ushort* Chi = pool1;
  ushort* Clo = pool1 + 8192;
  ushort* Bhi = pool1 + 16384;
  ushort* Blo = pool1 + 24576;
  ushort* Whi = pool1;
  ushort* Wlo = pool1 + 16384;
  ushort* Xth = pool2;
  ushort* Xtl = pool2 + 8192;
  ushort* Bfh = pool2 + 16384;
  ushort* Bfl = pool2 + 24576;

  const int tid  = threadIdx.x;
  const int lane = tid & 63;
  const int w    = tid >> 6;
  const int l15  = lane & 15;
  const int l4   = lane >> 4;
  const int c    = blockIdx.x & 31;
  const int hh   = (blockIdx.x >> 5) & 31;
  const int b    = blockIdx.x >> 10;
  const size_t m0 = (size_t)b * 4096 + c * QCH;
  const int slot  = (b * 32 + hh) * NCH + c;

  if (tid < 128) {
    dts[tid] = dtb[(m0 + tid) * 32 + hh];
    las[tid] = dtAb[(m0 + tid) * 32 + hh];
  }
  __syncthreads();
  for (int ofs = 1; ofs < 128; ofs <<= 1) {
    float v = 0.f;
    if (tid < 128 && tid >= ofs) v = las[tid - ofs];
    __syncthreads();
    if (tid < 128) las[tid] += v;
    __syncthreads();
  }
  if (tid < 128) {
    fqs[tid] = __expf(las[127] - las[tid]) * dts[tid];
    labuf[(size_t)slot * 128 + tid] = las[tid];
  }
  __syncthreads();

  {
    const int r = tid & 127, hf = tid >> 7;
    const float* rowp = conv + (m0 + r) * CSTRIDE;
    const float fqr = fqs[r];
    #pragma unroll
    for (int f = 0; f < 8; ++f) {
      const int c0 = hf * 32 + f * 4;
      float4 vc = *(const float4*)(rowp + 2112 + c0);
      ushort4 h, l;
      split4(vc, h, l);
      *(ushort4*)(Chi + CBI(r, c0)) = h;
      *(ushort4*)(Clo + CBI(r, c0)) = l;
      float4 vb = *(const float4*)(rowp + 2048 + c0);
      split4(vb, h, l);
      *(ushort4*)(Bhi + CBI(r, c0)) = h;
      *(ushort4*)(Blo + CBI(r, c0)) = l;
      float fb[4] = {vb.x * fqr, vb.y * fqr, vb.z * fqr, vb.w * fqr};
      #pragma unroll
      for (int e = 0; e < 4; ++e) {
        ushort hh2 = f2bf_rne(fb[e]);
        Bfh[TXI(c0 + e, r)] = hh2;
        Bfl[TXI(c0 + e, r)] = f2bf_rne(fb[e] - bf2f(hh2));
      }
      float4 vx = *(const float4*)(rowp + hh * 64 + c0);
      float fx[4] = {vx.x, vx.y, vx.z, vx.w};
      #pragma unroll
      for (int e = 0; e < 4; ++e) {
        ushort hh2 = f2bf_rne(fx[e]);
        Xth[TXI(c0 + e, r)] = hh2;
        Xtl[TXI(c0 + e, r)] = f2bf_rne(fx[e] - bf2f(hh2));
      }
    }
  }
  __syncthreads();

  f32x4 g[2][8];
  #pragma unroll
  for (int ti = 0; ti < 2; ++ti)
    #pragma unroll
    for (int tj = 0; tj < 8; ++tj) g[ti][tj] = (f32x4)0.f;

  #pragma unroll
  for (int ks = 0; ks < 2; ++ks) {
    const int kb = ks * 32 + l4 * 8;
    bf16x8 ca[2][2], bb[8][2];
    #pragma unroll
    for (int ti = 0; ti < 2; ++ti) {
      const int row = 32 * w + ti * 16 + l15;
      ca[ti][0] = *(const bf16x8*)(Chi + CBI(row, kb));
      ca[ti][1] = *(const bf16x8*)(Clo + CBI(row, kb));
    }
    #pragma unroll
    for (int tj = 0; tj < 8; ++tj) {
      const int jr = tj * 16 + l15;
      bb[tj][0] = *(const bf16x8*)(Bhi + CBI(jr, kb));
      bb[tj][1] = *(const bf16x8*)(Blo + CBI(jr, kb));
    }
    #pragma unroll
    for (int ti = 0; ti < 2; ++ti)
      #pragma unroll
      for (int tj = 0; tj < 8; ++tj) {
        g[ti][tj] = __builtin_amdgcn_mfma_f32_16x16x32_bf16(ca[ti][0], bb[tj][0], g[ti][tj], 0, 0, 0);
        g[ti][tj] = __builtin_amdgcn_mfma_f32_16x16x32_bf16(ca[ti][0], bb[tj][1], g[ti][tj], 0, 0, 0);
        g[ti][tj] = __builtin_amdgcn_mfma_f32_16x16x32_bf16(ca[ti][1], bb[tj][0], g[ti][tj], 0, 0, 0);
      }
  }
  __syncthreads();

  #pragma unroll
  for (int ti = 0; ti < 2; ++ti) {
    const int ib = 32 * w + ti * 16 + l4 * 4;
    #pragma unroll
    for (int tj = 0; tj < 8; ++tj) {
      const int j = tj * 16 + l15;
      const float laj = las[j], dj = dts[j];
      #pragma unroll
      for (int q = 0; q < 4; ++q) {
        const int i = ib + q;
        float wv = (j <= i) ? g[ti][tj][q] * __expf(las[i] - laj) * dj : 0.f;
        ushort h = f2bf_rne(wv);
        Whi[TXI(i, j)] = h;
        Wlo[TXI(i, j)] = f2bf_rne(wv - bf2f(h));
      }
    }
  }

  f32x4 y[2][4];
  #pragma unroll
  for (int ti = 0; ti < 2; ++ti)
    #pragma unroll
    for (int tp = 0; tp < 4; ++tp) y[ti][tp] = (f32x4)0.f;

  #pragma unroll
  for (int ks = 0; ks < 4; ++ks) {
    const int kb = ks * 32 + l4 * 8;
    bf16x8 wa[2][2], xb[4][2];
    #pragma unroll
    for (int ti = 0; ti < 2; ++ti) {
      const int row = 32 * w + ti * 16 + l15;
      wa[ti][0] = *(const bf16x8*)(Whi + TXI(row, kb));
      wa[ti][1] = *(const bf16x8*)(Wlo + TXI(row, kb));
    }
    #pragma unroll
    for (int tp = 0; tp < 4; ++tp) {
      const int p = tp * 16 + l15;
      xb[tp][0] = *(const bf16x8*)(Xth + TXI(p, kb));
      xb[tp][1] = *(const bf16x8*)(Xtl + TXI(p, kb));
    }
    #pragma unroll
    for (int ti = 0; ti < 2; ++ti)
      #pragma unroll
      for (int tp = 0; tp < 4; ++tp) {
        y[ti][tp] = __builtin_amdgcn_mfma_f32_16x16x32_bf16(wa[ti][0], xb[tp][0], y[ti][tp], 0, 0, 0);
        y[ti][tp] = __builtin_amdgcn_mfma_f32_16x16x32_bf16(wa[ti][0], xb[tp][1], y[ti][tp], 0, 0, 0);
        y[ti][tp] = __builtin_amdgcn_mfma_f32_16x16x32_bf16(wa[ti][1], xb[tp][0], y[ti][tp], 0, 0, 0);
      }
  }
  #pragma unroll
  for (int ti = 0; ti < 2; ++ti) {
    #pragma unroll
    for (int tp = 0; tp < 4; ++tp) {
      const int p = tp * 16 + l15;
      #pragma unroll
      for (int q = 0; q < 4; ++q) {
        const int i = 32 * w + ti * 16 + l4 * 4 + q;
        zx[(m0 + i) * LSTRIDE + 2048 + hh * 64 + p] = y[ti][tp][q];
      }
    }
  }

  f32x4 s[4];
  #pragma unroll
  for (int tn = 0; tn < 4; ++tn) s[tn] = (f32x4)0.f;
  #pragma unroll
  for (int ks = 0; ks < 4; ++ks) {
    const int kb = ks * 32 + l4 * 8;
    bf16x8 xa[2], bf[4][2];
    {
      const int p = 16 * w + l15;
      xa[0] = *(const bf16x8*)(Xth + TXI(p, kb));
      xa[1] = *(const bf16x8*)(Xtl + TXI(p, kb));
    }
    #pragma unroll
    for (int tn = 0; tn < 4; ++tn) {
      const int n = tn * 16 + l15;
      bf[tn][0] = *(const bf16x8*)(Bfh + TXI(n, kb));
      bf[tn][1] = *(const bf16x8*)(Bfl + TXI(n, kb));
    }
    #pragma unroll
    for (int tn = 0; tn < 4; ++tn) {
      s[tn] = __builtin_amdgcn_mfma_f32_16x16x32_bf16(xa[0], bf[tn][0], s[tn], 0, 0, 0);
      s[tn] = __builtin_amdgcn_mfma_f32_16x16x32_bf16(xa[0], bf[tn][1], s[tn], 0, 0, 0);
      s[tn] = __builtin_amdgcn_mfma_f32_16x16x32_bf16(xa[1], bf[tn][0], s[tn], 0, 0, 0);
    }
  }
  #pragma unroll
  for (int tn = 0; tn < 4; ++tn) {
    const int n = tn * 16 + l15;
    #pragma unroll
    for (int q = 0; q < 4; ++q) {
      const int p = 16 * w + l4 * 4 + q;
      Sbuf[(size_t)slot * 4096 + n * 64 + p] = s[tn][q];
    }
  }
}

// --------- K4b: chunk-state recurrence -------------------------------------
__global__ __launch_bounds__(256) void state_scan(
    float* __restrict__ Sbuf, const float* __restrict__ labuf) {
  const int bh = blockIdx.x >> 4;
  const int e  = (blockIdx.x & 15) * 256 + threadIdx.x;
  __shared__ float cq[NCH];
  if (threadIdx.x < NCH)
    cq[threadIdx.x] = __expf(labuf[((size_t)bh * NCH + threadIdx.x) * 128 + 127]);
  __syncthreads();
  float s = 0.f;
  float* base = Sbuf + (size_t)bh * NCH * 4096 + e;
  #pragma unroll 4
  for (int c = 0; c < NCH; ++c) {
    const float sv = base[c * 4096];
    base[c * 4096] = s;
    s = fmaf(cq[c], s, sv);
  }
}

// --------- K4c: Y += exp(la_i) * C @ sin + D*x ------------------------------
__global__ __launch_bounds__(256) void chunk_out(
    const float* __restrict__ conv, const float* __restrict__ Sbuf,
    const float* __restrict__ labuf, const float* __restrict__ Dv,
    float* __restrict__ zx) {
  __shared__ float Ct[64][132];
  __shared__ float Sin[64][65];
  __shared__ float las[128];

  const int tid  = threadIdx.x;
  const int lane = tid & 63;
  const int w    = tid >> 6;
  const int c    = blockIdx.x & 31;
  const int hh   = (blockIdx.x >> 5) & 31;
  const int b    = blockIdx.x >> 10;
  const size_t m0 = (size_t)b * 4096 + c * QCH;
  const int slot  = (b * 32 + hh) * NCH + c;

  {
    const int r = tid & 127, piece = tid >> 7;
    const float* rowp = conv + (m0 + r) * CSTRIDE;
    #pragma unroll
    for (int f = 0; f < 8; ++f) {
      const int n0 = piece * 32 + f * 4;
      float4 v = *(const float4*)(rowp + 2112 + n0);
      Ct[n0][r] = v.x; Ct[n0+1][r] = v.y; Ct[n0+2][r] = v.z; Ct[n0+3][r] = v.w;
    }
    #pragma unroll
    for (int f = 0; f < 4; ++f) {
      const int idx = tid * 16 + f * 4;
      float4 v = *(const float4*)(Sbuf + (size_t)slot * 4096 + idx);
      const int n = idx >> 6, p = idx & 63;
      Sin[n][p] = v.x; Sin[n][p+1] = v.y; Sin[n][p+2] = v.z; Sin[n][p+3] = v.w;
    }
    if (tid < 128) las[tid] = labuf[(size_t)slot * 128 + tid];
  }
  __syncthreads();

  const int r0 = w * 32;
  float acc[32];
  #pragma unroll
  for (int r = 0; r < 32; ++r) acc[r] = 0.f;
  #pragma unroll 2
  for (int n = 0; n < 64; ++n) {
    const float sv = Sin[n][lane];
    #pragma unroll
    for (int r4 = 0; r4 < 8; ++r4) {
      float4 c4 = *(const float4*)&Ct[n][r0 + r4 * 4];
      acc[r4*4+0] = fmaf(c4.x, sv, acc[r4*4+0]);
      acc[r4*4+1] = fmaf(c4.y, sv, acc[r4*4+1]);
      acc[r4*4+2] = fmaf(c4.z, sv, acc[r4*4+2]);
      acc[r4*4+3] = fmaf(c4.w, sv, acc[r4*4+3]);
    }
  }
  const float Dh = Dv[hh];
  #pragma unroll
  for (int r = 0; r < 32; ++r) {
    const int i = r0 + r;
    const size_t off = (m0 + i) * LSTRIDE + 2048 + hh * 64 + lane;
    const float xv = conv[(m0 + i) * CSTRIDE + hh * 64 + lane];
    zx[off] = zx[off] + __expf(las[i]) * acc[r] + Dh * xv;
  }
}

// --------- K4f: fallback serial scan ---------------------------------------
__global__ __launch_bounds__(256) void scan_kernel_fb(
    const float* __restrict__ conv, const float* __restrict__ dt_buf,
    const float* __restrict__ dtA_buf, const float* __restrict__ Dv,
    float* __restrict__ yout) {
  const int wid  = blockIdx.x * 4 + (threadIdx.x >> 6);
  const int lane = threadIdx.x & 63;
  const int b = wid >> 11;
  const int h = (wid >> 6) & 31;
  const int p = wid & 63;
  const size_t m0 = (size_t)b * 4096;
  const float* cx  = conv + m0 * CSTRIDE + h * 64 + p;
  const float* cB  = conv + m0 * CSTRIDE + 2048 + lane;
  const float* cC  = cB + 64;
  const float* cdA = dtA_buf + m0 * 32 + h;
  const float* cdt = dt_buf + m0 * 32 + h;
  float* yo = yout + m0 * LSTRIDE + 2048 + h * 64 + p;
  const float Dh = Dv[h];
  float s = 0.f;
  #pragma unroll 2
  for (int t = 0; t < 4096; ++t) {
    float xv  = cx[(size_t)t * CSTRIDE];
    float Bv  = cB[(size_t)t * CSTRIDE];
    float Cv  = cC[(size_t)t * CSTRIDE];
    float dAv = __expf(cdA[t * 32]);
    float dtv = cdt[t * 32];
    s = fmaf(s, dAv, dtv * xv * Bv);
    float prod = s * Cv;
    #pragma unroll
    for (int msk = 1; msk < 64; msk <<= 1) prod += __shfl_xor(prod, msk, 64);
    if (lane == 0) yo[(size_t)t * LSTRIDE] = fmaf(Dh, xv, prod);
  }
}

// ------- K5: gate + RMSNorm -> bf16 hi/lo (for the K6 bf16 GEMM) -----------
__global__ __launch_bounds__(256) void norm_kernel(
    const float* __restrict__ zx, const float* __restrict__ nw,
    ushort* __restrict__ ynh, ushort* __restrict__ ynl) {
  const int row = blockIdx.x, tid = threadIdx.x;
  const float* z = zx + (size_t)row * LSTRIDE;
  const float* y = z + 2048;
  float g[8];
  float ss = 0.f;
  #pragma unroll
  for (int j = 0; j < 2; ++j) {
    const int col = j * 1024 + tid * 4;
    float4 yv = *(const float4*)&y[col];
    float4 zv = *(const float4*)&z[col];
    float gs[4];
    gs[0] = yv.x * (zv.x / (1.f + expf(-zv.x)));
    gs[1] = yv.y * (zv.y / (1.f + expf(-zv.y)));
    gs[2] = yv.z * (zv.z / (1.f + expf(-zv.z)));
    gs[3] = yv.w * (zv.w / (1.f + expf(-zv.w)));
    #pragma unroll
    for (int q = 0; q < 4; ++q) { g[j * 4 + q] = gs[q]; ss += gs[q] * gs[q]; }
  }
  #pragma unroll
  for (int msk = 1; msk < 64; msk <<= 1) ss += __shfl_xor(ss, msk, 64);
  __shared__ float sred[4];
  if ((tid & 63) == 0) sred[tid >> 6] = ss;
  __syncthreads();
  ss = sred[0] + sred[1] + sred[2] + sred[3];
  const float scale = rsqrtf(ss * (1.f / 2048.f) + 1e-5f);
  #pragma unroll
  for (int j = 0; j < 2; ++j) {
    const int col = j * 1024 + tid * 4;
    float4 ov;
    ov.x = g[j * 4 + 0] * scale * nw[col + 0];
    ov.y = g[j * 4 + 1] * scale * nw[col + 1];
    ov.z = g[j * 4 + 2] * scale * nw[col + 2];
    ov.w = g[j * 4 + 3] * scale * nw[col + 3];
    ushort4 h, l;
    split4(ov, h, l);
    *(ushort4*)(ynh + (size_t)row * 2048 + col) = h;
    *(ushort4*)(ynl + (size_t)row * 2048 + col) = l;
  }
}

// ---------------------------------------------------------------------------
extern "C" void kernel_launch(void* const* d_in, const int* in_sizes, int n_in,
                              void* d_out, int out_size, void* d_ws, size_t ws_size,
                              hipStream_t stream) {
  const float* x       = (const float*)d_in[0];
  const float* W_in    = (const float*)d_in[1];
  const float* conv_w  = (const float*)d_in[2];
  const float* conv_b  = (const float*)d_in[3];
  const float* dt_bias = (const float*)d_in[4];
  const float* A_log   = (const float*)d_in[5];
  const float* Dv      = (const float*)d_in[6];
  const float* nw      = (const float*)d_in[7];
  const float* W_out   = (const float*)d_in[8];
  float* out = (float*)d_out;

  float* zx    = (float*)d_ws;
  float* conv  = zx + (size_t)MROWS * LSTRIDE;
  float* dtb   = conv + (size_t)MROWS * CSTRIDE;
  float* dtAb  = dtb + (size_t)MROWS * 32;
  float* Sbuf  = dtAb + (size_t)MROWS * 32;
  float* labuf = Sbuf + (size_t)64 * NCH * 4096;

  // bf16 split buffers aliasing dead phases of conv / Sbuf regions
  ushort* xh   = (ushort*)conv;               // dead after K1 (K3 overwrites)
  ushort* xl   = xh + 8388608;
  ushort* wht  = xh + 16777216;
  ushort* wlt  = xh + 21102592;
  ushort* ynh  = (ushort*)conv;               // written after K4c consumed conv
  ushort* ynl  = ynh + 16777216;
  ushort* woth = (ushort*)Sbuf;               // written after chunk_out
  ushort* wotl = woth + 2097152;

  const size_t NEED_CHUNKED = 246415360;
  const bool chunked = (ws_size >= NEED_CHUNKED);

  // K0a/K0b: one-time operand split (+transpose for B)
  split_x<<<2048, 256, 0, stream>>>(x, xh, xl, 2097152);
  split_transpose<<<dim3(66, 16), 256, 0, stream>>>(W_in, 4256, wht, wlt, 1024);
  // K1: zx = x @ W_in[:,0:4224]   (grid 33*64 = 2112, %8==0)
  gemm_bf16pre<128><<<2112, 256, 0, stream>>>(xh, xl, wht, wlt, zx, 1024, LSTRIDE, 33);
  // K2: dt (fp32 exact)
  dt_kernel<<<MROWS, 256, 0, stream>>>(x, W_in, dt_bias, A_log, dtb, dtAb);
  // K3: conv (overwrites xh/xl/wht/wlt region)
  conv_kernel<<<dim3(9, MROWS), 256, 0, stream>>>(zx, conv_w, conv_b, conv);

  if (chunked) {
    chunk_intra<<<2048, 256, 0, stream>>>(conv, dtb, dtAb, zx, Sbuf, labuf);
    state_scan<<<1024, 256, 0, stream>>>(Sbuf, labuf);
    chunk_out<<<2048, 256, 0, stream>>>(conv, Sbuf, labuf, Dv, zx);
  } else {
    scan_kernel_fb<<<1024, 256, 0, stream>>>(conv, dtb, dtAb, Dv, zx);
  }

  // K0c: split+transpose W_out into Sbuf region (dead after chunk_out)
  split_transpose<<<dim3(16, 32), 256, 0, stream>>>(W_out, 1024, woth, wotl, 2048);
  // K5: norm -> bf16 hi/lo into conv region (conv dead after K4c)
  norm_kernel<<<MROWS, 256, 0, stream>>>(zx, nw, ynh, ynl);
  // K6: out = yn @ W_out   (grid 16*64 = 1024, %8==0, BN=64)
  gemm_bf16pre<64><<<1024, 256, 0, stream>>>(ynh, ynl, woth, wotl, out, 2048, 1024, 16);
}